// Round 5
// baseline (483.579 us; speedup 1.0000x reference)
//
#include <hip/hip_runtime.h>
#include <hip/hip_bf16.h>
#include <math.h>

#define NN 32768
#define UU 16384
#define EE 1048576
#define NB 512      // dst buckets
#define NPB 64      // nodes per bucket (NN/NB)
#define SB 512      // scatter blocks
#define EPB 2048    // edges per scatter block (EE/SB)
#define CAP 2560    // bucket capacity (mean 2048, sigma~45 -> 11 sigma slack)

typedef __attribute__((ext_vector_type(8))) short bf16x8;
typedef __attribute__((ext_vector_type(4))) float f32x4;

__device__ __forceinline__ float sigf(float v) { return 1.0f / (1.0f + expf(-v)); }

// ---------------- Kernel A: m = emb[x] @ ggc^T  (+ zero gcount in block 0) ----------------
__global__ __launch_bounds__(256) void prep_m_k(const int* __restrict__ x,
                                                const float* __restrict__ emb,
                                                const float* __restrict__ ggc,
                                                float* __restrict__ m,
                                                int* __restrict__ gcount) {
    if (blockIdx.x == 0) {   // zero 512 padded counters (512*16 ints = 32KB)
        int4 z = make_int4(0, 0, 0, 0);
        for (int t = threadIdx.x; t < NB * 4; t += 256) ((int4*)gcount)[t] = z;
    }
    __shared__ float w[256];
    w[threadIdx.x] = ggc[threadIdx.x];
    __syncthreads();
    int i = blockIdx.x * 256 + threadIdx.x;
    int xi = x[i];
    float xe[16];
    const float4* s4 = (const float4*)(emb + (size_t)xi * 16);
#pragma unroll
    for (int q = 0; q < 4; ++q) {
        float4 v = s4[q];
        xe[4*q] = v.x; xe[4*q+1] = v.y; xe[4*q+2] = v.z; xe[4*q+3] = v.w;
    }
    float o[16];
#pragma unroll
    for (int j = 0; j < 16; ++j) {
        float acc = 0.0f;
#pragma unroll
        for (int k = 0; k < 16; ++k) acc += xe[k] * w[j*16 + k];
        o[j] = acc;
    }
    float4* d4 = (float4*)(m + (size_t)i * 16);
#pragma unroll
    for (int q = 0; q < 4; ++q) d4[q] = make_float4(o[4*q], o[4*q+1], o[4*q+2], o[4*q+3]);
}

// ---------------- Fused bucketing: histogram -> global range reservation -> place ----------------
__global__ __launch_bounds__(256) void scatter_fused_k(const int* __restrict__ e,
                                                       const float* __restrict__ h,
                                                       int* __restrict__ gcount,
                                                       uint2* __restrict__ sorted) {
    __shared__ int h1[NB], h2[NB], base[NB];
    for (int t = threadIdx.x; t < NB; t += 256) { h1[t] = 0; h2[t] = 0; }
    __syncthreads();
    int eb = blockIdx.x * EPB;
    const int4*   sp = (const int4*)(e + eb);
    const int4*   dp = (const int4*)(e + EE + eb);
    const float4* wp = (const float4*)(h + eb);
    int4   s0 = sp[threadIdx.x], s1 = sp[threadIdx.x + 256];
    int4   d0 = dp[threadIdx.x], d1 = dp[threadIdx.x + 256];
    float4 w0 = wp[threadIdx.x], w1 = wp[threadIdx.x + 256];
    // pass 1: per-block histogram (LDS atomics)
    atomicAdd(&h1[d0.x >> 6], 1); atomicAdd(&h1[d0.y >> 6], 1);
    atomicAdd(&h1[d0.z >> 6], 1); atomicAdd(&h1[d0.w >> 6], 1);
    atomicAdd(&h1[d1.x >> 6], 1); atomicAdd(&h1[d1.y >> 6], 1);
    atomicAdd(&h1[d1.z >> 6], 1); atomicAdd(&h1[d1.w >> 6], 1);
    __syncthreads();
    // reserve per-bucket ranges with one global atomic per (block,bucket); counters 64B-padded
    for (int t = threadIdx.x; t < NB; t += 256) {
        int c = h1[t];
        base[t] = c ? atomicAdd(&gcount[t * 16], c) : 0;
    }
    __syncthreads();
    // pass 2: place
#define PLACE(dv, sv, wv) { int b_ = (dv) >> 6; int off_ = atomicAdd(&h2[b_], 1); \
    sorted[(size_t)b_ * CAP + base[b_] + off_] = \
        make_uint2(((unsigned)(sv) << 6) | (unsigned)((dv) & 63), __float_as_uint(wv)); }
    PLACE(d0.x, s0.x, w0.x) PLACE(d0.y, s0.y, w0.y)
    PLACE(d0.z, s0.z, w0.z) PLACE(d0.w, s0.w, w0.w)
    PLACE(d1.x, s1.x, w1.x) PLACE(d1.y, s1.y, w1.y)
    PLACE(d1.z, s1.z, w1.z) PLACE(d1.w, s1.w, w1.w)
#undef PLACE
}

// ---------------- Aggregate per bucket in LDS, write mean ----------------
__global__ __launch_bounds__(256) void agg_k(const uint2* __restrict__ sorted,
                                             const int* __restrict__ gcount,
                                             const float* __restrict__ m, float* __restrict__ aggmean) {
    __shared__ float acc[NPB * 17];   // stride 17 to spread banks
    __shared__ int cnt[NPB];
    int b = blockIdx.x;
    for (int t = threadIdx.x; t < NPB * 17; t += 256) acc[t] = 0.0f;
    if (threadIdx.x < NPB) cnt[threadIdx.x] = 0;
    __syncthreads();
    int nb = gcount[b * 16];
    const uint2* seg = sorted + (size_t)b * CAP;
    for (int i = threadIdx.x; i < nb; i += 256) {
        uint2 ev = seg[i];
        int key = ev.x;
        float w = __uint_as_float(ev.y);
        int src = key >> 6;
        int dl  = key & 63;
        const float4* mp = (const float4*)(m + (size_t)src * 16);
        float* ap = &acc[dl * 17];
#pragma unroll
        for (int q = 0; q < 4; ++q) {
            float4 v = mp[q];
            atomicAdd(ap + 4*q + 0, v.x * w);
            atomicAdd(ap + 4*q + 1, v.y * w);
            atomicAdd(ap + 4*q + 2, v.z * w);
            atomicAdd(ap + 4*q + 3, v.w * w);
        }
        atomicAdd(&cnt[dl], 1);
    }
    __syncthreads();
    for (int t = threadIdx.x; t < NPB * 16; t += 256) {
        int dl = t >> 4, j = t & 15;
        float inv = 1.0f / fmaxf((float)cnt[dl], 1.0f);
        aggmean[(size_t)b * NPB * 16 + t] = acc[dl * 17 + j] * inv;
    }
}

// ---------------- Kernel C: per-node GRU + LSTM fused ----------------
__global__ __launch_bounds__(256) void node_k(
    const int* __restrict__ x, const float* __restrict__ emb,
    const float* __restrict__ aggmean,
    const float* __restrict__ h0g, const float* __restrict__ c0g,
    const float* __restrict__ gwi, const float* __restrict__ gwh,
    const float* __restrict__ gbi, const float* __restrict__ gbh,
    const float* __restrict__ lwi, const float* __restrict__ lwh,
    const float* __restrict__ lbi, const float* __restrict__ lbh,
    float* __restrict__ out_h, float* __restrict__ out_c, ushort* __restrict__ yb) {
    __shared__ float s_gwi[768], s_gwh[768], s_gbi[48], s_gbh[48];
    __shared__ float s_lwi[2048], s_lwh[4096], s_lbi[128], s_lbh[128];
    for (int t = threadIdx.x; t < 768; t += 256) { s_gwi[t] = gwi[t]; s_gwh[t] = gwh[t]; }
    if (threadIdx.x < 48) { s_gbi[threadIdx.x] = gbi[threadIdx.x]; s_gbh[threadIdx.x] = gbh[threadIdx.x]; }
    for (int t = threadIdx.x; t < 2048; t += 256) s_lwi[t] = lwi[t];
    for (int t = threadIdx.x; t < 4096; t += 256) s_lwh[t] = lwh[t];
    if (threadIdx.x < 128) { s_lbi[threadIdx.x] = lbi[threadIdx.x]; s_lbh[threadIdx.x] = lbh[threadIdx.x]; }
    __syncthreads();

    int i = blockIdx.x * 256 + threadIdx.x;
    float a[16], xe[16];
    {
        const float4* p = (const float4*)(aggmean + (size_t)i * 16);
#pragma unroll
        for (int q = 0; q < 4; ++q) {
            float4 v = p[q];
            a[4*q] = v.x; a[4*q+1] = v.y; a[4*q+2] = v.z; a[4*q+3] = v.w;
        }
        int xi = x[i];
        const float4* p2 = (const float4*)(emb + (size_t)xi * 16);
#pragma unroll
        for (int q = 0; q < 4; ++q) {
            float4 v = p2[q];
            xe[4*q] = v.x; xe[4*q+1] = v.y; xe[4*q+2] = v.z; xe[4*q+3] = v.w;
        }
    }
    // GRU
    float ht[16];
#pragma unroll 4
    for (int f = 0; f < 16; ++f) {
        float ir = s_gbi[f],    iz = s_gbi[16+f], in_ = s_gbi[32+f];
        float hr = s_gbh[f],    hz = s_gbh[16+f], hn  = s_gbh[32+f];
#pragma unroll
        for (int k = 0; k < 16; ++k) {
            float av = a[k], xv = xe[k];
            ir  += av * s_gwi[f*16 + k];
            iz  += av * s_gwi[(16+f)*16 + k];
            in_ += av * s_gwi[(32+f)*16 + k];
            hr  += xv * s_gwh[f*16 + k];
            hz  += xv * s_gwh[(16+f)*16 + k];
            hn  += xv * s_gwh[(32+f)*16 + k];
        }
        float r = sigf(ir + hr);
        float z = sigf(iz + hz);
        float n = tanhf(in_ + r * hn);
        ht[f] = (1.0f - z) * n + z * xe[f];
    }
    // LSTM
    float h0v[32];
    const float4* ph = (const float4*)(h0g + (size_t)i * 32);
#pragma unroll
    for (int q = 0; q < 8; ++q) {
        float4 v = ph[q];
        h0v[4*q] = v.x; h0v[4*q+1] = v.y; h0v[4*q+2] = v.z; h0v[4*q+3] = v.w;
    }
#pragma unroll
    for (int g = 0; g < 4; ++g) {
        float c0v[8];
        {
            float4 ca = *(const float4*)(c0g + (size_t)i * 32 + g * 8);
            float4 cb = *(const float4*)(c0g + (size_t)i * 32 + g * 8 + 4);
            c0v[0]=ca.x; c0v[1]=ca.y; c0v[2]=ca.z; c0v[3]=ca.w;
            c0v[4]=cb.x; c0v[5]=cb.y; c0v[6]=cb.z; c0v[7]=cb.w;
        }
        float cnv[8], hnv[8];
        ushort yv[8];
#pragma unroll
        for (int jj = 0; jj < 8; ++jj) {
            int j = g * 8 + jj;
            float ig = s_lbi[j]      + s_lbh[j];
            float fg = s_lbi[32+j]   + s_lbh[32+j];
            float gg = s_lbi[64+j]   + s_lbh[64+j];
            float og = s_lbi[96+j]   + s_lbh[96+j];
#pragma unroll
            for (int k = 0; k < 16; ++k) {
                float hv = ht[k];
                ig += hv * s_lwi[j*16 + k];
                fg += hv * s_lwi[(32+j)*16 + k];
                gg += hv * s_lwi[(64+j)*16 + k];
                og += hv * s_lwi[(96+j)*16 + k];
            }
#pragma unroll
            for (int k = 0; k < 32; ++k) {
                float hv = h0v[k];
                ig += hv * s_lwh[j*32 + k];
                fg += hv * s_lwh[(32+j)*32 + k];
                gg += hv * s_lwh[(64+j)*32 + k];
                og += hv * s_lwh[(96+j)*32 + k];
            }
            float cn  = sigf(fg) * c0v[jj] + sigf(ig) * tanhf(gg);
            float hn2 = sigf(og) * tanhf(cn);
            cnv[jj] = cn; hnv[jj] = hn2;
            __hip_bfloat16 t = __float2bfloat16(fmaxf(hn2, 0.0f));
            yv[jj] = *(ushort*)&t;
        }
        *(float4*)(out_c + (size_t)i*32 + g*8)     = make_float4(cnv[0],cnv[1],cnv[2],cnv[3]);
        *(float4*)(out_c + (size_t)i*32 + g*8 + 4) = make_float4(cnv[4],cnv[5],cnv[6],cnv[7]);
        *(float4*)(out_h + (size_t)i*32 + g*8)     = make_float4(hnv[0],hnv[1],hnv[2],hnv[3]);
        *(float4*)(out_h + (size_t)i*32 + g*8 + 4) = make_float4(hnv[4],hnv[5],hnv[6],hnv[7]);
        uint4 yq;
        yq.x = (unsigned)yv[0] | ((unsigned)yv[1] << 16);
        yq.y = (unsigned)yv[2] | ((unsigned)yv[3] << 16);
        yq.z = (unsigned)yv[4] | ((unsigned)yv[5] << 16);
        yq.w = (unsigned)yv[6] | ((unsigned)yv[7] << 16);
        *(uint4*)(yb + (size_t)i*32 + g*8) = yq;
    }
}

// ---------------- Kernel D: scores = y_u @ y_i^T via bf16 MFMA ----------------
// R3 geometry (best measured): block tile 64 rows x 256 cols, wave tile 16x256.
// Non-temporal stores: 1.07 GB zero-reuse stream, keep it out of L2.
__global__ __launch_bounds__(256) void scores_mfma_k(const ushort* __restrict__ yb,
                                                     float* __restrict__ out) {
    int tid = threadIdx.x;
    int w = tid >> 6, l = tid & 63;
    int bx = blockIdx.x & 63;     // 64 col-blocks of 256
    int by = blockIdx.x >> 6;     // 256 row-blocks of 64
    int row0 = by * 64 + w * 16;
    int col0 = bx * 256;
    int lr = l & 15;
    int lk = (l >> 4) << 3;       // 0,8,16,24
    bf16x8 a = *(const bf16x8*)(yb + (size_t)(row0 + lr) * 32 + lk);
    const ushort* yi = yb + (size_t)(UU + col0) * 32;
    f32x4 acc[16];
#pragma unroll
    for (int ct = 0; ct < 16; ++ct) {
        bf16x8 b = *(const bf16x8*)(yi + (size_t)(ct * 16 + lr) * 32 + lk);
        acc[ct] = __builtin_amdgcn_mfma_f32_16x16x32_bf16(a, b, (f32x4){0.0f,0.0f,0.0f,0.0f}, 0, 0, 0);
    }
    int orow = row0 + ((l >> 4) << 2);
#pragma unroll
    for (int ct = 0; ct < 16; ++ct) {
        float* p = out + (size_t)orow * UU + col0 + ct * 16 + lr;
#pragma unroll
        for (int r = 0; r < 4; ++r)
            __builtin_nontemporal_store(acc[ct][r], p + (size_t)r * UU);
    }
}

extern "C" void kernel_launch(void* const* d_in, const int* in_sizes, int n_in,
                              void* d_out, int out_size, void* d_ws, size_t ws_size,
                              hipStream_t stream) {
    const int*   x   = (const int*)d_in[0];
    const int*   e   = (const int*)d_in[1];
    const float* h   = (const float*)d_in[2];
    const float* h0  = (const float*)d_in[3];
    const float* c0  = (const float*)d_in[4];
    const float* emb = (const float*)d_in[5];
    const float* ggc = (const float*)d_in[6];
    const float* gwi = (const float*)d_in[7];
    const float* gwh = (const float*)d_in[8];
    const float* gbi = (const float*)d_in[9];
    const float* gbh = (const float*)d_in[10];
    const float* lwi = (const float*)d_in[11];
    const float* lwh = (const float*)d_in[12];
    const float* lbi = (const float*)d_in[13];
    const float* lbh = (const float*)d_in[14];

    float* out    = (float*)d_out;
    float* scores = out;
    float* out_h  = out + (size_t)UU * UU;
    float* out_c  = out_h + (size_t)NN * 32;

    char* ws = (char*)d_ws;
    float*  m       = (float*)(ws);                    // 2 MB
    float*  aggmean = (float*)(ws + (2u << 20));       // 2 MB
    ushort* yb      = (ushort*)(ws + (4u << 20));      // NN*32 bf16 = 2 MB
    int*    gcount  = (int*)  (ws + (8u << 20));       // 512 counters, 64B-padded = 32 KB

    // 512*2560*8B = 10.5 MB sorted-edge scratch inside the scores output
    // region (fully overwritten by scores_mfma_k afterwards).
    uint2* sorted  = (uint2*)((char*)d_out + (512u << 20));

    prep_m_k<<<NN / 256, 256, 0, stream>>>(x, emb, ggc, m, gcount);
    scatter_fused_k<<<SB, 256, 0, stream>>>(e, h, gcount, sorted);
    agg_k<<<NB, 256, 0, stream>>>(sorted, gcount, m, aggmean);
    node_k<<<NN / 256, 256, 0, stream>>>(x, emb, aggmean, h0, c0,
                                         gwi, gwh, gbi, gbh,
                                         lwi, lwh, lbi, lbh,
                                         out_h, out_c, yb);
    scores_mfma_k<<<256 * 64, 256, 0, stream>>>(yb, scores);
}

// Round 6
// 402.928 us; speedup vs baseline: 1.2002x; 1.2002x over previous
//
#include <hip/hip_runtime.h>
#include <hip/hip_bf16.h>
#include <math.h>

#define NN 32768
#define UU 16384
#define EE 1048576
#define NB 512      // dst buckets
#define NPB 64      // nodes per bucket (NN/NB)
#define SB 512      // hist/scatter blocks
#define EPB 2048    // edges per hist/scatter block (EE/SB)

typedef __attribute__((ext_vector_type(8))) short bf16x8;
typedef __attribute__((ext_vector_type(4))) float f32x4;

__device__ __forceinline__ float sigf(float v) { return 1.0f / (1.0f + expf(-v)); }

// ---------------- Kernel A: m = emb[x] @ ggc^T ----------------
__global__ __launch_bounds__(256) void prep_m_k(const int* __restrict__ x,
                                                const float* __restrict__ emb,
                                                const float* __restrict__ ggc,
                                                float* __restrict__ m) {
    __shared__ float w[256];
    w[threadIdx.x] = ggc[threadIdx.x];
    __syncthreads();
    int i = blockIdx.x * 256 + threadIdx.x;
    int xi = x[i];
    float xe[16];
    const float4* s4 = (const float4*)(emb + (size_t)xi * 16);
#pragma unroll
    for (int q = 0; q < 4; ++q) {
        float4 v = s4[q];
        xe[4*q] = v.x; xe[4*q+1] = v.y; xe[4*q+2] = v.z; xe[4*q+3] = v.w;
    }
    float o[16];
#pragma unroll
    for (int j = 0; j < 16; ++j) {
        float acc = 0.0f;
#pragma unroll
        for (int k = 0; k < 16; ++k) acc += xe[k] * w[j*16 + k];
        o[j] = acc;
    }
    float4* d4 = (float4*)(m + (size_t)i * 16);
#pragma unroll
    for (int q = 0; q < 4; ++q) d4[q] = make_float4(o[4*q], o[4*q+1], o[4*q+2], o[4*q+3]);
}

// ---------------- Sort phase 1: per-block histogram over dst buckets ----------------
__global__ __launch_bounds__(256) void hist_k(const int* __restrict__ e, int* __restrict__ hist) {
    __shared__ int h[NB];
    for (int t = threadIdx.x; t < NB; t += 256) h[t] = 0;
    __syncthreads();
    int base = blockIdx.x * EPB;
#pragma unroll
    for (int k = 0; k < 8; ++k) {
        int d = e[EE + base + threadIdx.x + k * 256];
        atomicAdd(&h[d >> 6], 1);          // LDS atomic
    }
    __syncthreads();
    for (int t = threadIdx.x; t < NB; t += 256) hist[t * SB + blockIdx.x] = h[t];
}

// ---------------- Sort phase 2a: bucket totals ----------------
__global__ __launch_bounds__(256) void scan1_k(const int* __restrict__ hist, int* __restrict__ btot) {
    int b = blockIdx.x;
    int s = hist[b * SB + threadIdx.x] + hist[b * SB + 256 + threadIdx.x];
    __shared__ int sm[256];
    sm[threadIdx.x] = s;
    __syncthreads();
    for (int o = 128; o > 0; o >>= 1) {
        if (threadIdx.x < o) sm[threadIdx.x] += sm[threadIdx.x + o];
        __syncthreads();
    }
    if (threadIdx.x == 0) btot[b] = sm[0];
}

// ---------------- Sort phase 2b: exclusive scan of bucket totals ----------------
__global__ __launch_bounds__(256) void scan2_k(const int* __restrict__ btot, int* __restrict__ bbase) {
    int t = threadIdx.x;
    int a  = btot[2 * t];
    int b2 = btot[2 * t + 1];
    int tsum = a + b2;
    __shared__ int sm[256];
    sm[t] = tsum;
    __syncthreads();
    for (int o = 1; o < 256; o <<= 1) {
        int v = (t >= o) ? sm[t - o] : 0;
        __syncthreads();
        sm[t] += v;
        __syncthreads();
    }
    int excl = sm[t] - tsum;
    bbase[2 * t]     = excl;
    bbase[2 * t + 1] = excl + a;
    if (t == 255) bbase[512] = excl + tsum;
}

// ---------------- Sort phase 2c: per-bucket exclusive scan over blocks -> offsets ----------------
__global__ __launch_bounds__(256) void scan3_k(int* __restrict__ hist, const int* __restrict__ bbase) {
    int b = blockIdx.x;
    int t = threadIdx.x;
    int e0 = hist[b * SB + 2 * t];
    int e1 = hist[b * SB + 2 * t + 1];
    int tsum = e0 + e1;
    __shared__ int sm[256];
    sm[t] = tsum;
    __syncthreads();
    for (int o = 1; o < 256; o <<= 1) {
        int v = (t >= o) ? sm[t - o] : 0;
        __syncthreads();
        sm[t] += v;
        __syncthreads();
    }
    int excl = sm[t] - tsum + bbase[b];
    hist[b * SB + 2 * t]     = excl;
    hist[b * SB + 2 * t + 1] = excl + e0;
}

// ---------------- Sort phase 3: scatter edges into dst-bucket order ----------------
__global__ __launch_bounds__(256) void scatter_k(const int* __restrict__ e, const float* __restrict__ h,
                                                 const int* __restrict__ offs, uint2* __restrict__ sorted) {
    __shared__ int loff[NB];
    for (int t = threadIdx.x; t < NB; t += 256) loff[t] = offs[t * SB + blockIdx.x];
    __syncthreads();
    int base = blockIdx.x * EPB;
#pragma unroll
    for (int k = 0; k < 8; ++k) {
        int i = base + threadIdx.x + k * 256;
        int src = e[i];
        int dst = e[EE + i];
        float w = h[i];
        int pos = atomicAdd(&loff[dst >> 6], 1);   // LDS atomic
        sorted[pos] = make_uint2(((unsigned)src << 6) | (unsigned)(dst & 63), __float_as_uint(w));
    }
}

// ---------------- Aggregate per bucket in LDS, write mean ----------------
__global__ __launch_bounds__(256) void agg_k(const uint2* __restrict__ sorted, const int* __restrict__ bbase,
                                             const float* __restrict__ m, float* __restrict__ aggmean) {
    __shared__ float acc[NPB * 17];   // stride 17 to spread banks
    __shared__ int cnt[NPB];
    int b = blockIdx.x;
    for (int t = threadIdx.x; t < NPB * 17; t += 256) acc[t] = 0.0f;
    if (threadIdx.x < NPB) cnt[threadIdx.x] = 0;
    __syncthreads();
    int s0 = bbase[b], s1 = bbase[b + 1];
    for (int i = s0 + threadIdx.x; i < s1; i += 256) {
        uint2 ev = sorted[i];
        int key = ev.x;
        float w = __uint_as_float(ev.y);
        int src = key >> 6;
        int dl  = key & 63;
        const float4* mp = (const float4*)(m + (size_t)src * 16);
        float* ap = &acc[dl * 17];
#pragma unroll
        for (int q = 0; q < 4; ++q) {
            float4 v = mp[q];
            atomicAdd(ap + 4*q + 0, v.x * w);
            atomicAdd(ap + 4*q + 1, v.y * w);
            atomicAdd(ap + 4*q + 2, v.z * w);
            atomicAdd(ap + 4*q + 3, v.w * w);
        }
        atomicAdd(&cnt[dl], 1);
    }
    __syncthreads();
    for (int t = threadIdx.x; t < NPB * 16; t += 256) {
        int dl = t >> 4, j = t & 15;
        float inv = 1.0f / fmaxf((float)cnt[dl], 1.0f);
        aggmean[(size_t)b * NPB * 16 + t] = acc[dl * 17 + j] * inv;
    }
}

// ---------------- Kernel C: per-node GRU + LSTM fused ----------------
__global__ __launch_bounds__(256) void node_k(
    const int* __restrict__ x, const float* __restrict__ emb,
    const float* __restrict__ aggmean,
    const float* __restrict__ h0g, const float* __restrict__ c0g,
    const float* __restrict__ gwi, const float* __restrict__ gwh,
    const float* __restrict__ gbi, const float* __restrict__ gbh,
    const float* __restrict__ lwi, const float* __restrict__ lwh,
    const float* __restrict__ lbi, const float* __restrict__ lbh,
    float* __restrict__ out_h, float* __restrict__ out_c, ushort* __restrict__ yb) {
    __shared__ float s_gwi[768], s_gwh[768], s_gbi[48], s_gbh[48];
    __shared__ float s_lwi[2048], s_lwh[4096], s_lbi[128], s_lbh[128];
    for (int t = threadIdx.x; t < 768; t += 256) { s_gwi[t] = gwi[t]; s_gwh[t] = gwh[t]; }
    if (threadIdx.x < 48) { s_gbi[threadIdx.x] = gbi[threadIdx.x]; s_gbh[threadIdx.x] = gbh[threadIdx.x]; }
    for (int t = threadIdx.x; t < 2048; t += 256) s_lwi[t] = lwi[t];
    for (int t = threadIdx.x; t < 4096; t += 256) s_lwh[t] = lwh[t];
    if (threadIdx.x < 128) { s_lbi[threadIdx.x] = lbi[threadIdx.x]; s_lbh[threadIdx.x] = lbh[threadIdx.x]; }
    __syncthreads();

    int i = blockIdx.x * 256 + threadIdx.x;
    float a[16], xe[16];
    {
        const float4* p = (const float4*)(aggmean + (size_t)i * 16);
#pragma unroll
        for (int q = 0; q < 4; ++q) {
            float4 v = p[q];
            a[4*q] = v.x; a[4*q+1] = v.y; a[4*q+2] = v.z; a[4*q+3] = v.w;
        }
        int xi = x[i];
        const float4* p2 = (const float4*)(emb + (size_t)xi * 16);
#pragma unroll
        for (int q = 0; q < 4; ++q) {
            float4 v = p2[q];
            xe[4*q] = v.x; xe[4*q+1] = v.y; xe[4*q+2] = v.z; xe[4*q+3] = v.w;
        }
    }
    // GRU
    float ht[16];
#pragma unroll 4
    for (int f = 0; f < 16; ++f) {
        float ir = s_gbi[f],    iz = s_gbi[16+f], in_ = s_gbi[32+f];
        float hr = s_gbh[f],    hz = s_gbh[16+f], hn  = s_gbh[32+f];
#pragma unroll
        for (int k = 0; k < 16; ++k) {
            float av = a[k], xv = xe[k];
            ir  += av * s_gwi[f*16 + k];
            iz  += av * s_gwi[(16+f)*16 + k];
            in_ += av * s_gwi[(32+f)*16 + k];
            hr  += xv * s_gwh[f*16 + k];
            hz  += xv * s_gwh[(16+f)*16 + k];
            hn  += xv * s_gwh[(32+f)*16 + k];
        }
        float r = sigf(ir + hr);
        float z = sigf(iz + hz);
        float n = tanhf(in_ + r * hn);
        ht[f] = (1.0f - z) * n + z * xe[f];
    }
    // LSTM
    float h0v[32];
    const float4* ph = (const float4*)(h0g + (size_t)i * 32);
#pragma unroll
    for (int q = 0; q < 8; ++q) {
        float4 v = ph[q];
        h0v[4*q] = v.x; h0v[4*q+1] = v.y; h0v[4*q+2] = v.z; h0v[4*q+3] = v.w;
    }
#pragma unroll
    for (int g = 0; g < 4; ++g) {
        float c0v[8];
        {
            float4 ca = *(const float4*)(c0g + (size_t)i * 32 + g * 8);
            float4 cb = *(const float4*)(c0g + (size_t)i * 32 + g * 8 + 4);
            c0v[0]=ca.x; c0v[1]=ca.y; c0v[2]=ca.z; c0v[3]=ca.w;
            c0v[4]=cb.x; c0v[5]=cb.y; c0v[6]=cb.z; c0v[7]=cb.w;
        }
        float cnv[8], hnv[8];
        ushort yv[8];
#pragma unroll
        for (int jj = 0; jj < 8; ++jj) {
            int j = g * 8 + jj;
            float ig = s_lbi[j]      + s_lbh[j];
            float fg = s_lbi[32+j]   + s_lbh[32+j];
            float gg = s_lbi[64+j]   + s_lbh[64+j];
            float og = s_lbi[96+j]   + s_lbh[96+j];
#pragma unroll
            for (int k = 0; k < 16; ++k) {
                float hv = ht[k];
                ig += hv * s_lwi[j*16 + k];
                fg += hv * s_lwi[(32+j)*16 + k];
                gg += hv * s_lwi[(64+j)*16 + k];
                og += hv * s_lwi[(96+j)*16 + k];
            }
#pragma unroll
            for (int k = 0; k < 32; ++k) {
                float hv = h0v[k];
                ig += hv * s_lwh[j*32 + k];
                fg += hv * s_lwh[(32+j)*32 + k];
                gg += hv * s_lwh[(64+j)*32 + k];
                og += hv * s_lwh[(96+j)*32 + k];
            }
            float cn  = sigf(fg) * c0v[jj] + sigf(ig) * tanhf(gg);
            float hn2 = sigf(og) * tanhf(cn);
            cnv[jj] = cn; hnv[jj] = hn2;
            __hip_bfloat16 t = __float2bfloat16(fmaxf(hn2, 0.0f));
            yv[jj] = *(ushort*)&t;
        }
        *(float4*)(out_c + (size_t)i*32 + g*8)     = make_float4(cnv[0],cnv[1],cnv[2],cnv[3]);
        *(float4*)(out_c + (size_t)i*32 + g*8 + 4) = make_float4(cnv[4],cnv[5],cnv[6],cnv[7]);
        *(float4*)(out_h + (size_t)i*32 + g*8)     = make_float4(hnv[0],hnv[1],hnv[2],hnv[3]);
        *(float4*)(out_h + (size_t)i*32 + g*8 + 4) = make_float4(hnv[4],hnv[5],hnv[6],hnv[7]);
        uint4 yq;
        yq.x = (unsigned)yv[0] | ((unsigned)yv[1] << 16);
        yq.y = (unsigned)yv[2] | ((unsigned)yv[3] << 16);
        yq.z = (unsigned)yv[4] | ((unsigned)yv[5] << 16);
        yq.w = (unsigned)yv[6] | ((unsigned)yv[7] << 16);
        *(uint4*)(yb + (size_t)i*32 + g*8) = yq;
    }
}

// ---------------- Kernel D: scores = y_u @ y_i^T via bf16 MFMA ----------------
// R3 geometry: block tile 64 rows x 256 cols; wave tile 16 x 256 (16 MFMA).
// NEW: epilogue transposes acc through per-wave LDS so stores are
// global_store_dwordx4 with 256B-contiguous 16-lane groups.
__global__ __launch_bounds__(256) void scores_mfma_k(const ushort* __restrict__ yb,
                                                     float* __restrict__ out) {
    __shared__ float tr[4][16][68];   // per-wave 16x64 tile, stride 68 (16B-aligned rows, bank-spread)
    int tid = threadIdx.x;
    int w = tid >> 6, l = tid & 63;
    int bx = blockIdx.x & 63;     // 64 col-blocks of 256
    int by = blockIdx.x >> 6;     // 256 row-blocks of 64
    int row0 = by * 64 + w * 16;
    int col0 = bx * 256;
    int lr = l & 15;
    int lk = (l >> 4) << 3;       // 0,8,16,24
    bf16x8 a = *(const bf16x8*)(yb + (size_t)(row0 + lr) * 32 + lk);
    const ushort* yi = yb + (size_t)(UU + col0) * 32;
    f32x4 acc[16];
#pragma unroll
    for (int ct = 0; ct < 16; ++ct) {
        bf16x8 b = *(const bf16x8*)(yi + (size_t)(ct * 16 + lr) * 32 + lk);
        acc[ct] = __builtin_amdgcn_mfma_f32_16x16x32_bf16(a, b, (f32x4){0.0f,0.0f,0.0f,0.0f}, 0, 0, 0);
    }
    float* lw = &tr[w][0][0];
    int G = l >> 4;               // 0..3
#pragma unroll
    for (int g = 0; g < 4; ++g) {
        // write phase: 4 ct-tiles (64 cols) into [16][68] LDS tile
#pragma unroll
        for (int ct2 = 0; ct2 < 4; ++ct2)
#pragma unroll
            for (int r = 0; r < 4; ++r)
                lw[(G * 4 + r) * 68 + ct2 * 16 + lr] = acc[g * 4 + ct2][r];
        // read phase (intra-wave, lgkmcnt-ordered): each lane = 4 consecutive cols of one row
#pragma unroll
        for (int i = 0; i < 4; ++i) {
            int rl = 4 * i + G;
            float4 v = *(const float4*)&lw[rl * 68 + lr * 4];
            *(float4*)(out + (size_t)(row0 + rl) * UU + col0 + g * 64 + lr * 4) = v;
        }
    }
}

extern "C" void kernel_launch(void* const* d_in, const int* in_sizes, int n_in,
                              void* d_out, int out_size, void* d_ws, size_t ws_size,
                              hipStream_t stream) {
    const int*   x   = (const int*)d_in[0];
    const int*   e   = (const int*)d_in[1];
    const float* h   = (const float*)d_in[2];
    const float* h0  = (const float*)d_in[3];
    const float* c0  = (const float*)d_in[4];
    const float* emb = (const float*)d_in[5];
    const float* ggc = (const float*)d_in[6];
    const float* gwi = (const float*)d_in[7];
    const float* gwh = (const float*)d_in[8];
    const float* gbi = (const float*)d_in[9];
    const float* gbh = (const float*)d_in[10];
    const float* lwi = (const float*)d_in[11];
    const float* lwh = (const float*)d_in[12];
    const float* lbi = (const float*)d_in[13];
    const float* lbh = (const float*)d_in[14];

    float* out    = (float*)d_out;
    float* scores = out;
    float* out_h  = out + (size_t)UU * UU;
    float* out_c  = out_h + (size_t)NN * 32;

    char* ws = (char*)d_ws;
    float*  m       = (float*)(ws);                    // 2 MB
    float*  aggmean = (float*)(ws + (2u << 20));       // 2 MB
    ushort* yb      = (ushort*)(ws + (4u << 20));      // NN*32 bf16 = 2 MB
    int*    hist    = (int*)  (ws + (8u << 20));       // NB*SB ints = 1 MB
    int*    btot    = (int*)  (ws + (9u << 20));       // 2 KB
    int*    bbase   = (int*)  (ws + (9u << 20) + 4096);// 2052 B

    // 8 MB sorted-edge scratch inside the scores output region (fully
    // overwritten by scores_mfma_k afterwards).
    uint2* sorted  = (uint2*)((char*)d_out + (512u << 20));

    prep_m_k<<<NN / 256, 256, 0, stream>>>(x, emb, ggc, m);
    hist_k<<<SB, 256, 0, stream>>>(e, hist);
    scan1_k<<<NB, 256, 0, stream>>>(hist, btot);
    scan2_k<<<1, 256, 0, stream>>>(btot, bbase);
    scan3_k<<<NB, 256, 0, stream>>>(hist, bbase);
    scatter_k<<<SB, 256, 0, stream>>>(e, h, hist, sorted);
    agg_k<<<NB, 256, 0, stream>>>(sorted, bbase, m, aggmean);
    node_k<<<NN / 256, 256, 0, stream>>>(x, emb, aggmean, h0, c0,
                                         gwi, gwh, gbi, gbh,
                                         lwi, lwh, lbi, lbh,
                                         out_h, out_c, yb);
    scores_mfma_k<<<256 * 64, 256, 0, stream>>>(yb, scores);
}

// Round 7
// 395.390 us; speedup vs baseline: 1.2230x; 1.0191x over previous
//
#include <hip/hip_runtime.h>
#include <hip/hip_bf16.h>
#include <math.h>

#define NN 32768
#define UU 16384
#define EE 1048576
#define NB 512      // dst buckets
#define NPB 64      // nodes per bucket (NN/NB)
#define SB2 128     // fused scatter blocks
#define EPB2 8192   // edges per scatter block (EE/SB2)
#define CAP 2560    // bucket capacity (mean 2048, sigma~45 -> 11 sigma slack)

typedef __attribute__((ext_vector_type(8))) short bf16x8;
typedef __attribute__((ext_vector_type(4))) float f32x4;

__device__ __forceinline__ float sigf(float v) { return 1.0f / (1.0f + expf(-v)); }

// ---------------- Kernel A: m = emb[x] @ ggc^T  (+ zero gcount in block 0) ----------------
__global__ __launch_bounds__(256) void prep_m_k(const int* __restrict__ x,
                                                const float* __restrict__ emb,
                                                const float* __restrict__ ggc,
                                                float* __restrict__ m,
                                                int* __restrict__ gcount) {
    if (blockIdx.x == 0) {   // zero 512 padded counters (512*16 ints = 32KB)
        int4 z = make_int4(0, 0, 0, 0);
        for (int t = threadIdx.x; t < NB * 4; t += 256) ((int4*)gcount)[t] = z;
    }
    __shared__ float w[256];
    w[threadIdx.x] = ggc[threadIdx.x];
    __syncthreads();
    int i = blockIdx.x * 256 + threadIdx.x;
    int xi = x[i];
    float xe[16];
    const float4* s4 = (const float4*)(emb + (size_t)xi * 16);
#pragma unroll
    for (int q = 0; q < 4; ++q) {
        float4 v = s4[q];
        xe[4*q] = v.x; xe[4*q+1] = v.y; xe[4*q+2] = v.z; xe[4*q+3] = v.w;
    }
    float o[16];
#pragma unroll
    for (int j = 0; j < 16; ++j) {
        float acc = 0.0f;
#pragma unroll
        for (int k = 0; k < 16; ++k) acc += xe[k] * w[j*16 + k];
        o[j] = acc;
    }
    float4* d4 = (float4*)(m + (size_t)i * 16);
#pragma unroll
    for (int q = 0; q < 4; ++q) d4[q] = make_float4(o[4*q], o[4*q+1], o[4*q+2], o[4*q+3]);
}

// ---------------- Fused bucketing: hist -> global range reservation -> place ----------------
// Two passes over the block's 8192 edges (second read is L2-hit).
__global__ __launch_bounds__(256) void scatter_fused_k(const int* __restrict__ e,
                                                       const float* __restrict__ h,
                                                       int* __restrict__ gcount,
                                                       uint2* __restrict__ sorted) {
    __shared__ int h1[NB], h2[NB], base[NB];
    for (int t = threadIdx.x; t < NB; t += 256) { h1[t] = 0; h2[t] = 0; }
    __syncthreads();
    int eb = blockIdx.x * EPB2;
    const int4*   sp = (const int4*)(e + eb);
    const int4*   dp = (const int4*)(e + EE + eb);
    const float4* wp = (const float4*)(h + eb);
    // pass 1: per-block histogram (LDS atomics)
#pragma unroll
    for (int k = 0; k < 8; ++k) {
        int4 d = dp[threadIdx.x + k * 256];
        atomicAdd(&h1[d.x >> 6], 1); atomicAdd(&h1[d.y >> 6], 1);
        atomicAdd(&h1[d.z >> 6], 1); atomicAdd(&h1[d.w >> 6], 1);
    }
    __syncthreads();
    // reserve per-bucket ranges: one global atomic per (block,bucket); counters 64B-padded
    for (int t = threadIdx.x; t < NB; t += 256) {
        int c = h1[t];
        base[t] = c ? atomicAdd(&gcount[t * 16], c) : 0;
    }
    __syncthreads();
    // pass 2: re-read and place
#define PLACE(dv, sv, wv) { int b_ = (dv) >> 6; int off_ = atomicAdd(&h2[b_], 1); \
    sorted[(size_t)b_ * CAP + base[b_] + off_] = \
        make_uint2(((unsigned)(sv) << 6) | (unsigned)((dv) & 63), __float_as_uint(wv)); }
#pragma unroll
    for (int k = 0; k < 8; ++k) {
        int idx = threadIdx.x + k * 256;
        int4   s = sp[idx];
        int4   d = dp[idx];
        float4 wv = wp[idx];
        PLACE(d.x, s.x, wv.x) PLACE(d.y, s.y, wv.y)
        PLACE(d.z, s.z, wv.z) PLACE(d.w, s.w, wv.w)
    }
#undef PLACE
}

// ---------------- Aggregate per bucket in LDS, write mean ----------------
__global__ __launch_bounds__(256) void agg_k(const uint2* __restrict__ sorted,
                                             const int* __restrict__ gcount,
                                             const float* __restrict__ m, float* __restrict__ aggmean) {
    __shared__ float acc[NPB * 17];   // stride 17 to spread banks
    __shared__ int cnt[NPB];
    int b = blockIdx.x;
    for (int t = threadIdx.x; t < NPB * 17; t += 256) acc[t] = 0.0f;
    if (threadIdx.x < NPB) cnt[threadIdx.x] = 0;
    __syncthreads();
    int nb = gcount[b * 16];
    const uint2* seg = sorted + (size_t)b * CAP;
    for (int i = threadIdx.x; i < nb; i += 256) {
        uint2 ev = seg[i];
        int key = ev.x;
        float w = __uint_as_float(ev.y);
        int src = key >> 6;
        int dl  = key & 63;
        const float4* mp = (const float4*)(m + (size_t)src * 16);
        float* ap = &acc[dl * 17];
#pragma unroll
        for (int q = 0; q < 4; ++q) {
            float4 v = mp[q];
            atomicAdd(ap + 4*q + 0, v.x * w);
            atomicAdd(ap + 4*q + 1, v.y * w);
            atomicAdd(ap + 4*q + 2, v.z * w);
            atomicAdd(ap + 4*q + 3, v.w * w);
        }
        atomicAdd(&cnt[dl], 1);
    }
    __syncthreads();
    for (int t = threadIdx.x; t < NPB * 16; t += 256) {
        int dl = t >> 4, j = t & 15;
        float inv = 1.0f / fmaxf((float)cnt[dl], 1.0f);
        aggmean[(size_t)b * NPB * 16 + t] = acc[dl * 17 + j] * inv;
    }
}

// ---------------- Kernel C: per-node GRU + LSTM fused ----------------
__global__ __launch_bounds__(256) void node_k(
    const int* __restrict__ x, const float* __restrict__ emb,
    const float* __restrict__ aggmean,
    const float* __restrict__ h0g, const float* __restrict__ c0g,
    const float* __restrict__ gwi, const float* __restrict__ gwh,
    const float* __restrict__ gbi, const float* __restrict__ gbh,
    const float* __restrict__ lwi, const float* __restrict__ lwh,
    const float* __restrict__ lbi, const float* __restrict__ lbh,
    float* __restrict__ out_h, float* __restrict__ out_c, ushort* __restrict__ yb) {
    __shared__ float s_gwi[768], s_gwh[768], s_gbi[48], s_gbh[48];
    __shared__ float s_lwi[2048], s_lwh[4096], s_lbi[128], s_lbh[128];
    for (int t = threadIdx.x; t < 768; t += 256) { s_gwi[t] = gwi[t]; s_gwh[t] = gwh[t]; }
    if (threadIdx.x < 48) { s_gbi[threadIdx.x] = gbi[threadIdx.x]; s_gbh[threadIdx.x] = gbh[threadIdx.x]; }
    for (int t = threadIdx.x; t < 2048; t += 256) s_lwi[t] = lwi[t];
    for (int t = threadIdx.x; t < 4096; t += 256) s_lwh[t] = lwh[t];
    if (threadIdx.x < 128) { s_lbi[threadIdx.x] = lbi[threadIdx.x]; s_lbh[threadIdx.x] = lbh[threadIdx.x]; }
    __syncthreads();

    int i = blockIdx.x * 256 + threadIdx.x;
    float a[16], xe[16];
    {
        const float4* p = (const float4*)(aggmean + (size_t)i * 16);
#pragma unroll
        for (int q = 0; q < 4; ++q) {
            float4 v = p[q];
            a[4*q] = v.x; a[4*q+1] = v.y; a[4*q+2] = v.z; a[4*q+3] = v.w;
        }
        int xi = x[i];
        const float4* p2 = (const float4*)(emb + (size_t)xi * 16);
#pragma unroll
        for (int q = 0; q < 4; ++q) {
            float4 v = p2[q];
            xe[4*q] = v.x; xe[4*q+1] = v.y; xe[4*q+2] = v.z; xe[4*q+3] = v.w;
        }
    }
    // GRU
    float ht[16];
#pragma unroll 4
    for (int f = 0; f < 16; ++f) {
        float ir = s_gbi[f],    iz = s_gbi[16+f], in_ = s_gbi[32+f];
        float hr = s_gbh[f],    hz = s_gbh[16+f], hn  = s_gbh[32+f];
#pragma unroll
        for (int k = 0; k < 16; ++k) {
            float av = a[k], xv = xe[k];
            ir  += av * s_gwi[f*16 + k];
            iz  += av * s_gwi[(16+f)*16 + k];
            in_ += av * s_gwi[(32+f)*16 + k];
            hr  += xv * s_gwh[f*16 + k];
            hz  += xv * s_gwh[(16+f)*16 + k];
            hn  += xv * s_gwh[(32+f)*16 + k];
        }
        float r = sigf(ir + hr);
        float z = sigf(iz + hz);
        float n = tanhf(in_ + r * hn);
        ht[f] = (1.0f - z) * n + z * xe[f];
    }
    // LSTM
    float h0v[32];
    const float4* ph = (const float4*)(h0g + (size_t)i * 32);
#pragma unroll
    for (int q = 0; q < 8; ++q) {
        float4 v = ph[q];
        h0v[4*q] = v.x; h0v[4*q+1] = v.y; h0v[4*q+2] = v.z; h0v[4*q+3] = v.w;
    }
#pragma unroll
    for (int g = 0; g < 4; ++g) {
        float c0v[8];
        {
            float4 ca = *(const float4*)(c0g + (size_t)i * 32 + g * 8);
            float4 cb = *(const float4*)(c0g + (size_t)i * 32 + g * 8 + 4);
            c0v[0]=ca.x; c0v[1]=ca.y; c0v[2]=ca.z; c0v[3]=ca.w;
            c0v[4]=cb.x; c0v[5]=cb.y; c0v[6]=cb.z; c0v[7]=cb.w;
        }
        float cnv[8], hnv[8];
        ushort yv[8];
#pragma unroll
        for (int jj = 0; jj < 8; ++jj) {
            int j = g * 8 + jj;
            float ig = s_lbi[j]      + s_lbh[j];
            float fg = s_lbi[32+j]   + s_lbh[32+j];
            float gg = s_lbi[64+j]   + s_lbh[64+j];
            float og = s_lbi[96+j]   + s_lbh[96+j];
#pragma unroll
            for (int k = 0; k < 16; ++k) {
                float hv = ht[k];
                ig += hv * s_lwi[j*16 + k];
                fg += hv * s_lwi[(32+j)*16 + k];
                gg += hv * s_lwi[(64+j)*16 + k];
                og += hv * s_lwi[(96+j)*16 + k];
            }
#pragma unroll
            for (int k = 0; k < 32; ++k) {
                float hv = h0v[k];
                ig += hv * s_lwh[j*32 + k];
                fg += hv * s_lwh[(32+j)*32 + k];
                gg += hv * s_lwh[(64+j)*32 + k];
                og += hv * s_lwh[(96+j)*32 + k];
            }
            float cn  = sigf(fg) * c0v[jj] + sigf(ig) * tanhf(gg);
            float hn2 = sigf(og) * tanhf(cn);
            cnv[jj] = cn; hnv[jj] = hn2;
            __hip_bfloat16 t = __float2bfloat16(fmaxf(hn2, 0.0f));
            yv[jj] = *(ushort*)&t;
        }
        *(float4*)(out_c + (size_t)i*32 + g*8)     = make_float4(cnv[0],cnv[1],cnv[2],cnv[3]);
        *(float4*)(out_c + (size_t)i*32 + g*8 + 4) = make_float4(cnv[4],cnv[5],cnv[6],cnv[7]);
        *(float4*)(out_h + (size_t)i*32 + g*8)     = make_float4(hnv[0],hnv[1],hnv[2],hnv[3]);
        *(float4*)(out_h + (size_t)i*32 + g*8 + 4) = make_float4(hnv[4],hnv[5],hnv[6],hnv[7]);
        uint4 yq;
        yq.x = (unsigned)yv[0] | ((unsigned)yv[1] << 16);
        yq.y = (unsigned)yv[2] | ((unsigned)yv[3] << 16);
        yq.z = (unsigned)yv[4] | ((unsigned)yv[5] << 16);
        yq.w = (unsigned)yv[6] | ((unsigned)yv[7] << 16);
        *(uint4*)(yb + (size_t)i*32 + g*8) = yq;
    }
}

// ---------------- Kernel D: scores = y_u @ y_i^T via bf16 MFMA ----------------
// R6 version (measured equal-best): 64x256 block tile, LDS-transpose epilogue.
__global__ __launch_bounds__(256) void scores_mfma_k(const ushort* __restrict__ yb,
                                                     float* __restrict__ out) {
    __shared__ float tr[4][16][68];
    int tid = threadIdx.x;
    int w = tid >> 6, l = tid & 63;
    int bx = blockIdx.x & 63;     // 64 col-blocks of 256
    int by = blockIdx.x >> 6;     // 256 row-blocks of 64
    int row0 = by * 64 + w * 16;
    int col0 = bx * 256;
    int lr = l & 15;
    int lk = (l >> 4) << 3;       // 0,8,16,24
    bf16x8 a = *(const bf16x8*)(yb + (size_t)(row0 + lr) * 32 + lk);
    const ushort* yi = yb + (size_t)(UU + col0) * 32;
    f32x4 acc[16];
#pragma unroll
    for (int ct = 0; ct < 16; ++ct) {
        bf16x8 b = *(const bf16x8*)(yi + (size_t)(ct * 16 + lr) * 32 + lk);
        acc[ct] = __builtin_amdgcn_mfma_f32_16x16x32_bf16(a, b, (f32x4){0.0f,0.0f,0.0f,0.0f}, 0, 0, 0);
    }
    float* lw = &tr[w][0][0];
    int G = l >> 4;               // 0..3
#pragma unroll
    for (int g = 0; g < 4; ++g) {
#pragma unroll
        for (int ct2 = 0; ct2 < 4; ++ct2)
#pragma unroll
            for (int r = 0; r < 4; ++r)
                lw[(G * 4 + r) * 68 + ct2 * 16 + lr] = acc[g * 4 + ct2][r];
#pragma unroll
        for (int i = 0; i < 4; ++i) {
            int rl = 4 * i + G;
            float4 v = *(const float4*)&lw[rl * 68 + lr * 4];
            *(float4*)(out + (size_t)(row0 + rl) * UU + col0 + g * 64 + lr * 4) = v;
        }
    }
}

extern "C" void kernel_launch(void* const* d_in, const int* in_sizes, int n_in,
                              void* d_out, int out_size, void* d_ws, size_t ws_size,
                              hipStream_t stream) {
    const int*   x   = (const int*)d_in[0];
    const int*   e   = (const int*)d_in[1];
    const float* h   = (const float*)d_in[2];
    const float* h0  = (const float*)d_in[3];
    const float* c0  = (const float*)d_in[4];
    const float* emb = (const float*)d_in[5];
    const float* ggc = (const float*)d_in[6];
    const float* gwi = (const float*)d_in[7];
    const float* gwh = (const float*)d_in[8];
    const float* gbi = (const float*)d_in[9];
    const float* gbh = (const float*)d_in[10];
    const float* lwi = (const float*)d_in[11];
    const float* lwh = (const float*)d_in[12];
    const float* lbi = (const float*)d_in[13];
    const float* lbh = (const float*)d_in[14];

    float* out    = (float*)d_out;
    float* scores = out;
    float* out_h  = out + (size_t)UU * UU;
    float* out_c  = out_h + (size_t)NN * 32;

    char* ws = (char*)d_ws;
    float*  m       = (float*)(ws);                    // 2 MB
    float*  aggmean = (float*)(ws + (2u << 20));       // 2 MB
    ushort* yb      = (ushort*)(ws + (4u << 20));      // NN*32 bf16 = 2 MB
    int*    gcount  = (int*)  (ws + (8u << 20));       // 512 counters, 64B-padded = 32 KB

    // 512*2560*8B = 10.5 MB sorted-edge scratch inside the scores output
    // region (fully overwritten by scores_mfma_k afterwards).
    uint2* sorted  = (uint2*)((char*)d_out + (512u << 20));

    prep_m_k<<<NN / 256, 256, 0, stream>>>(x, emb, ggc, m, gcount);
    scatter_fused_k<<<SB2, 256, 0, stream>>>(e, h, gcount, sorted);
    agg_k<<<NB, 256, 0, stream>>>(sorted, gcount, m, aggmean);
    node_k<<<NN / 256, 256, 0, stream>>>(x, emb, aggmean, h0, c0,
                                         gwi, gwh, gbi, gbh,
                                         lwi, lwh, lbi, lbh,
                                         out_h, out_c, yb);
    scores_mfma_k<<<256 * 64, 256, 0, stream>>>(yb, scores);
}

// Round 8
// 373.208 us; speedup vs baseline: 1.2957x; 1.0594x over previous
//
#include <hip/hip_runtime.h>
#include <hip/hip_bf16.h>
#include <math.h>

#define NN 32768
#define UU 16384
#define EE 1048576
#define NB 512      // dst buckets
#define NPB 64      // nodes per bucket (NN/NB)
#define SB2 512     // fused scatter blocks (full CU coverage)
#define EPB2 2048   // edges per scatter block (EE/SB2)
#define CAP 2560    // bucket capacity (mean 2048, sigma~45 -> 11 sigma slack)

typedef __attribute__((ext_vector_type(8))) short bf16x8;
typedef __attribute__((ext_vector_type(4))) float f32x4;

__device__ __forceinline__ float sigf(float v) { return 1.0f / (1.0f + expf(-v)); }

// ---------------- Kernel A: m = emb[x] @ ggc^T  (+ zero gcount in block 0) ----------------
__global__ __launch_bounds__(256) void prep_m_k(const int* __restrict__ x,
                                                const float* __restrict__ emb,
                                                const float* __restrict__ ggc,
                                                float* __restrict__ m,
                                                int* __restrict__ gcount) {
    if (blockIdx.x == 0) {   // zero 512 padded counters (512*16 ints = 32KB)
        int4 z = make_int4(0, 0, 0, 0);
        for (int t = threadIdx.x; t < NB * 4; t += 256) ((int4*)gcount)[t] = z;
    }
    __shared__ float w[256];
    w[threadIdx.x] = ggc[threadIdx.x];
    __syncthreads();
    int i = blockIdx.x * 256 + threadIdx.x;
    int xi = x[i];
    float xe[16];
    const float4* s4 = (const float4*)(emb + (size_t)xi * 16);
#pragma unroll
    for (int q = 0; q < 4; ++q) {
        float4 v = s4[q];
        xe[4*q] = v.x; xe[4*q+1] = v.y; xe[4*q+2] = v.z; xe[4*q+3] = v.w;
    }
    float o[16];
#pragma unroll
    for (int j = 0; j < 16; ++j) {
        float acc = 0.0f;
#pragma unroll
        for (int k = 0; k < 16; ++k) acc += xe[k] * w[j*16 + k];
        o[j] = acc;
    }
    float4* d4 = (float4*)(m + (size_t)i * 16);
#pragma unroll
    for (int q = 0; q < 4; ++q) d4[q] = make_float4(o[4*q], o[4*q+1], o[4*q+2], o[4*q+3]);
}

// ---------------- Fused bucketing: hist -> global range reservation -> place ----------------
__global__ __launch_bounds__(256) void scatter_fused_k(const int* __restrict__ e,
                                                       const float* __restrict__ h,
                                                       int* __restrict__ gcount,
                                                       uint2* __restrict__ sorted) {
    __shared__ int h1[NB], h2[NB], base[NB];
    for (int t = threadIdx.x; t < NB; t += 256) { h1[t] = 0; h2[t] = 0; }
    __syncthreads();
    int eb = blockIdx.x * EPB2;
    const int4*   sp = (const int4*)(e + eb);
    const int4*   dp = (const int4*)(e + EE + eb);
    const float4* wp = (const float4*)(h + eb);
    // pass 1: per-block histogram (LDS atomics)
#pragma unroll
    for (int k = 0; k < 2; ++k) {
        int4 d = dp[threadIdx.x + k * 256];
        atomicAdd(&h1[d.x >> 6], 1); atomicAdd(&h1[d.y >> 6], 1);
        atomicAdd(&h1[d.z >> 6], 1); atomicAdd(&h1[d.w >> 6], 1);
    }
    __syncthreads();
    // reserve per-bucket ranges: one global atomic per (block,bucket); counters 64B-padded
    for (int t = threadIdx.x; t < NB; t += 256) {
        int c = h1[t];
        base[t] = c ? atomicAdd(&gcount[t * 16], c) : 0;
    }
    __syncthreads();
    // pass 2: re-read (L2-hot) and place
#define PLACE(dv, sv, wv) { int b_ = (dv) >> 6; int off_ = atomicAdd(&h2[b_], 1); \
    sorted[(size_t)b_ * CAP + base[b_] + off_] = \
        make_uint2(((unsigned)(sv) << 6) | (unsigned)((dv) & 63), __float_as_uint(wv)); }
#pragma unroll
    for (int k = 0; k < 2; ++k) {
        int idx = threadIdx.x + k * 256;
        int4   s = sp[idx];
        int4   d = dp[idx];
        float4 wv = wp[idx];
        PLACE(d.x, s.x, wv.x) PLACE(d.y, s.y, wv.y)
        PLACE(d.z, s.z, wv.z) PLACE(d.w, s.w, wv.w)
    }
#undef PLACE
}

// ---------------- Fused: bucket aggregation + GRU + LSTM (one block = one bucket of 64 nodes) ----------------
// Phase 1: all 256 threads accumulate weighted msgs into LDS (stride-17).
// Phase 2: normalize in place. Phase 3: 4 threads per node compute GRU (ht -> LDS).
// Phase 4: 4 threads per node compute 8 LSTM outputs each; write h,c,y(bf16).
__global__ __launch_bounds__(256) void aggnode_k(
    const uint2* __restrict__ sorted, const int* __restrict__ gcount,
    const float* __restrict__ m,
    const int* __restrict__ x, const float* __restrict__ emb,
    const float* __restrict__ h0g, const float* __restrict__ c0g,
    const float* __restrict__ gwi, const float* __restrict__ gwh,
    const float* __restrict__ gbi, const float* __restrict__ gbh,
    const float* __restrict__ lwi, const float* __restrict__ lwh,
    const float* __restrict__ lbi, const float* __restrict__ lbh,
    float* __restrict__ out_h, float* __restrict__ out_c, ushort* __restrict__ yb) {
    __shared__ float acc[NPB * 17];
    __shared__ int   cnt[NPB];
    __shared__ float s_ht[NPB * 17];
    __shared__ float s_gwi[768], s_gwh[768], s_gbi[48], s_gbh[48];
    __shared__ float s_lwi[2048], s_lwh[4096], s_lbi[128], s_lbh[128];

    int tid = threadIdx.x;
    for (int t = tid; t < NPB * 17; t += 256) acc[t] = 0.0f;
    if (tid < NPB) cnt[tid] = 0;
    // stage weights (overlaps with zeroing; all used after later barriers)
    for (int t = tid; t < 768; t += 256) { s_gwi[t] = gwi[t]; s_gwh[t] = gwh[t]; }
    if (tid < 48) { s_gbi[tid] = gbi[tid]; s_gbh[tid] = gbh[tid]; }
    for (int t = tid; t < 2048; t += 256) s_lwi[t] = lwi[t];
    for (int t = tid; t < 4096; t += 256) s_lwh[t] = lwh[t];
    if (tid < 128) { s_lbi[tid] = lbi[tid]; s_lbh[tid] = lbh[tid]; }
    __syncthreads();

    int b = blockIdx.x;
    // ---- Phase 1: aggregate ----
    int nb = gcount[b * 16];
    const uint2* seg = sorted + (size_t)b * CAP;
    for (int i = tid; i < nb; i += 256) {
        uint2 ev = seg[i];
        int key = ev.x;
        float w = __uint_as_float(ev.y);
        int src = key >> 6;
        int dl  = key & 63;
        const float4* mp = (const float4*)(m + (size_t)src * 16);
        float* ap = &acc[dl * 17];
#pragma unroll
        for (int q = 0; q < 4; ++q) {
            float4 v = mp[q];
            atomicAdd(ap + 4*q + 0, v.x * w);
            atomicAdd(ap + 4*q + 1, v.y * w);
            atomicAdd(ap + 4*q + 2, v.z * w);
            atomicAdd(ap + 4*q + 3, v.w * w);
        }
        atomicAdd(&cnt[dl], 1);
    }
    __syncthreads();
    // ---- Phase 2: normalize to mean, in place ----
    for (int t = tid; t < NPB * 16; t += 256) {
        int dl = t >> 4, j = t & 15;
        float inv = 1.0f / fmaxf((float)cnt[dl], 1.0f);
        acc[dl * 17 + j] *= inv;
    }
    __syncthreads();

    int n  = tid >> 2;        // node within bucket: 0..63
    int p  = tid & 3;         // part: 0..3
    int gn = b * NPB + n;     // global node
    // xe = emb[x[gn]]
    int xi = x[gn];
    float xe[16];
    {
        const float4* p2 = (const float4*)(emb + (size_t)xi * 16);
#pragma unroll
        for (int q = 0; q < 4; ++q) {
            float4 v = p2[q];
            xe[4*q] = v.x; xe[4*q+1] = v.y; xe[4*q+2] = v.z; xe[4*q+3] = v.w;
        }
    }
    // ---- Phase 3: GRU — 4 features per thread ----
    {
        const float* a = &acc[n * 17];
#pragma unroll
        for (int ff = 0; ff < 4; ++ff) {
            int f = p * 4 + ff;
            float ir = s_gbi[f],    iz = s_gbi[16+f], in_ = s_gbi[32+f];
            float hr = s_gbh[f],    hz = s_gbh[16+f], hn  = s_gbh[32+f];
#pragma unroll
            for (int k = 0; k < 16; ++k) {
                float av = a[k], xv = xe[k];
                ir  += av * s_gwi[f*16 + k];
                iz  += av * s_gwi[(16+f)*16 + k];
                in_ += av * s_gwi[(32+f)*16 + k];
                hr  += xv * s_gwh[f*16 + k];
                hz  += xv * s_gwh[(16+f)*16 + k];
                hn  += xv * s_gwh[(32+f)*16 + k];
            }
            float r = sigf(ir + hr);
            float z = sigf(iz + hz);
            float nn2 = tanhf(in_ + r * hn);
            s_ht[n * 17 + f] = (1.0f - z) * nn2 + z * xe[f];
        }
    }
    __syncthreads();
    // ---- Phase 4: LSTM — 8 outputs per thread ----
    {
        float h0v[32];
        const float4* ph = (const float4*)(h0g + (size_t)gn * 32);
#pragma unroll
        for (int q = 0; q < 8; ++q) {
            float4 v = ph[q];
            h0v[4*q] = v.x; h0v[4*q+1] = v.y; h0v[4*q+2] = v.z; h0v[4*q+3] = v.w;
        }
        float htv[16];
#pragma unroll
        for (int k = 0; k < 16; ++k) htv[k] = s_ht[n * 17 + k];
        float c0v[8];
        {
            float4 ca = *(const float4*)(c0g + (size_t)gn * 32 + p * 8);
            float4 cb = *(const float4*)(c0g + (size_t)gn * 32 + p * 8 + 4);
            c0v[0]=ca.x; c0v[1]=ca.y; c0v[2]=ca.z; c0v[3]=ca.w;
            c0v[4]=cb.x; c0v[5]=cb.y; c0v[6]=cb.z; c0v[7]=cb.w;
        }
        float cnv[8], hnv[8];
        ushort yv[8];
#pragma unroll
        for (int jj = 0; jj < 8; ++jj) {
            int j = p * 8 + jj;
            float ig = s_lbi[j]      + s_lbh[j];
            float fg = s_lbi[32+j]   + s_lbh[32+j];
            float gg = s_lbi[64+j]   + s_lbh[64+j];
            float og = s_lbi[96+j]   + s_lbh[96+j];
#pragma unroll
            for (int k = 0; k < 16; ++k) {
                float hv = htv[k];
                ig += hv * s_lwi[j*16 + k];
                fg += hv * s_lwi[(32+j)*16 + k];
                gg += hv * s_lwi[(64+j)*16 + k];
                og += hv * s_lwi[(96+j)*16 + k];
            }
#pragma unroll
            for (int k = 0; k < 32; ++k) {
                float hv = h0v[k];
                ig += hv * s_lwh[j*32 + k];
                fg += hv * s_lwh[(32+j)*32 + k];
                gg += hv * s_lwh[(64+j)*32 + k];
                og += hv * s_lwh[(96+j)*32 + k];
            }
            float cn  = sigf(fg) * c0v[jj] + sigf(ig) * tanhf(gg);
            float hn2 = sigf(og) * tanhf(cn);
            cnv[jj] = cn; hnv[jj] = hn2;
            __hip_bfloat16 t = __float2bfloat16(fmaxf(hn2, 0.0f));
            yv[jj] = *(ushort*)&t;
        }
        size_t ob = (size_t)gn * 32 + p * 8;
        *(float4*)(out_c + ob)     = make_float4(cnv[0],cnv[1],cnv[2],cnv[3]);
        *(float4*)(out_c + ob + 4) = make_float4(cnv[4],cnv[5],cnv[6],cnv[7]);
        *(float4*)(out_h + ob)     = make_float4(hnv[0],hnv[1],hnv[2],hnv[3]);
        *(float4*)(out_h + ob + 4) = make_float4(hnv[4],hnv[5],hnv[6],hnv[7]);
        uint4 yq;
        yq.x = (unsigned)yv[0] | ((unsigned)yv[1] << 16);
        yq.y = (unsigned)yv[2] | ((unsigned)yv[3] << 16);
        yq.z = (unsigned)yv[4] | ((unsigned)yv[5] << 16);
        yq.w = (unsigned)yv[6] | ((unsigned)yv[7] << 16);
        *(uint4*)(yb + ob) = yq;
    }
}

// ---------------- Kernel D: scores = y_u @ y_i^T via bf16 MFMA ----------------
// R6 version (measured equal-best): 64x256 block tile, LDS-transpose epilogue.
__global__ __launch_bounds__(256) void scores_mfma_k(const ushort* __restrict__ yb,
                                                     float* __restrict__ out) {
    __shared__ float tr[4][16][68];
    int tid = threadIdx.x;
    int w = tid >> 6, l = tid & 63;
    int bx = blockIdx.x & 63;     // 64 col-blocks of 256
    int by = blockIdx.x >> 6;     // 256 row-blocks of 64
    int row0 = by * 64 + w * 16;
    int col0 = bx * 256;
    int lr = l & 15;
    int lk = (l >> 4) << 3;       // 0,8,16,24
    bf16x8 a = *(const bf16x8*)(yb + (size_t)(row0 + lr) * 32 + lk);
    const ushort* yi = yb + (size_t)(UU + col0) * 32;
    f32x4 acc[16];
#pragma unroll
    for (int ct = 0; ct < 16; ++ct) {
        bf16x8 b = *(const bf16x8*)(yi + (size_t)(ct * 16 + lr) * 32 + lk);
        acc[ct] = __builtin_amdgcn_mfma_f32_16x16x32_bf16(a, b, (f32x4){0.0f,0.0f,0.0f,0.0f}, 0, 0, 0);
    }
    float* lw = &tr[w][0][0];
    int G = l >> 4;               // 0..3
#pragma unroll
    for (int g = 0; g < 4; ++g) {
#pragma unroll
        for (int ct2 = 0; ct2 < 4; ++ct2)
#pragma unroll
            for (int r = 0; r < 4; ++r)
                lw[(G * 4 + r) * 68 + ct2 * 16 + lr] = acc[g * 4 + ct2][r];
#pragma unroll
        for (int i = 0; i < 4; ++i) {
            int rl = 4 * i + G;
            float4 v = *(const float4*)&lw[rl * 68 + lr * 4];
            *(float4*)(out + (size_t)(row0 + rl) * UU + col0 + g * 64 + lr * 4) = v;
        }
    }
}

extern "C" void kernel_launch(void* const* d_in, const int* in_sizes, int n_in,
                              void* d_out, int out_size, void* d_ws, size_t ws_size,
                              hipStream_t stream) {
    const int*   x   = (const int*)d_in[0];
    const int*   e   = (const int*)d_in[1];
    const float* h   = (const float*)d_in[2];
    const float* h0  = (const float*)d_in[3];
    const float* c0  = (const float*)d_in[4];
    const float* emb = (const float*)d_in[5];
    const float* ggc = (const float*)d_in[6];
    const float* gwi = (const float*)d_in[7];
    const float* gwh = (const float*)d_in[8];
    const float* gbi = (const float*)d_in[9];
    const float* gbh = (const float*)d_in[10];
    const float* lwi = (const float*)d_in[11];
    const float* lwh = (const float*)d_in[12];
    const float* lbi = (const float*)d_in[13];
    const float* lbh = (const float*)d_in[14];

    float* out    = (float*)d_out;
    float* scores = out;
    float* out_h  = out + (size_t)UU * UU;
    float* out_c  = out_h + (size_t)NN * 32;

    char* ws = (char*)d_ws;
    float*  m       = (float*)(ws);                    // 2 MB
    ushort* yb      = (ushort*)(ws + (4u << 20));      // NN*32 bf16 = 2 MB
    int*    gcount  = (int*)  (ws + (8u << 20));       // 512 counters, 64B-padded = 32 KB

    // 512*2560*8B = 10.5 MB sorted-edge scratch inside the scores output
    // region (fully overwritten by scores_mfma_k afterwards).
    uint2* sorted  = (uint2*)((char*)d_out + (512u << 20));

    prep_m_k<<<NN / 256, 256, 0, stream>>>(x, emb, ggc, m, gcount);
    scatter_fused_k<<<SB2, 256, 0, stream>>>(e, h, gcount, sorted);
    aggnode_k<<<NB, 256, 0, stream>>>(sorted, gcount, m, x, emb, h0, c0,
                                      gwi, gwh, gbi, gbh,
                                      lwi, lwh, lbi, lbh,
                                      out_h, out_c, yb);
    scores_mfma_k<<<256 * 64, 256, 0, stream>>>(yb, scores);
}

// Round 9
// 318.500 us; speedup vs baseline: 1.5183x; 1.1718x over previous
//
#include <hip/hip_runtime.h>
#include <hip/hip_bf16.h>
#include <math.h>

#define NN 32768
#define UU 16384
#define EE 1048576
#define NB 512      // dst buckets
#define NPB 64      // nodes per bucket (NN/NB)
#define SB2 512     // fused scatter blocks (full CU coverage)
#define EPB2 2048   // edges per scatter block (EE/SB2)
#define CAP 2560    // bucket capacity (mean 2048, sigma~45 -> 11 sigma slack)

typedef __attribute__((ext_vector_type(8))) short bf16x8;
typedef __attribute__((ext_vector_type(4))) float f32x4;

__device__ __forceinline__ float sigf(float v) { return 1.0f / (1.0f + expf(-v)); }

// ---------------- Kernel A: m = emb[x] @ ggc^T  (+ zero gcount in block 0) ----------------
__global__ __launch_bounds__(256) void prep_m_k(const int* __restrict__ x,
                                                const float* __restrict__ emb,
                                                const float* __restrict__ ggc,
                                                float* __restrict__ m,
                                                int* __restrict__ gcount) {
    if (blockIdx.x == 0) {   // zero 512 padded counters (512*16 ints = 32KB)
        int4 z = make_int4(0, 0, 0, 0);
        for (int t = threadIdx.x; t < NB * 4; t += 256) ((int4*)gcount)[t] = z;
    }
    __shared__ float w[256];
    w[threadIdx.x] = ggc[threadIdx.x];
    __syncthreads();
    int i = blockIdx.x * 256 + threadIdx.x;
    int xi = x[i];
    float xe[16];
    const float4* s4 = (const float4*)(emb + (size_t)xi * 16);
#pragma unroll
    for (int q = 0; q < 4; ++q) {
        float4 v = s4[q];
        xe[4*q] = v.x; xe[4*q+1] = v.y; xe[4*q+2] = v.z; xe[4*q+3] = v.w;
    }
    float o[16];
#pragma unroll
    for (int j = 0; j < 16; ++j) {
        float acc = 0.0f;
#pragma unroll
        for (int k = 0; k < 16; ++k) acc += xe[k] * w[j*16 + k];
        o[j] = acc;
    }
    float4* d4 = (float4*)(m + (size_t)i * 16);
#pragma unroll
    for (int q = 0; q < 4; ++q) d4[q] = make_float4(o[4*q], o[4*q+1], o[4*q+2], o[4*q+3]);
}

// ---------------- Fused bucketing: hist -> global range reservation -> place ----------------
__global__ __launch_bounds__(256) void scatter_fused_k(const int* __restrict__ e,
                                                       const float* __restrict__ h,
                                                       int* __restrict__ gcount,
                                                       uint2* __restrict__ sorted) {
    __shared__ int h1[NB], h2[NB], base[NB];
    for (int t = threadIdx.x; t < NB; t += 256) { h1[t] = 0; h2[t] = 0; }
    __syncthreads();
    int eb = blockIdx.x * EPB2;
    const int4*   sp = (const int4*)(e + eb);
    const int4*   dp = (const int4*)(e + EE + eb);
    const float4* wp = (const float4*)(h + eb);
    // pass 1: per-block histogram (LDS atomics)
#pragma unroll
    for (int k = 0; k < 2; ++k) {
        int4 d = dp[threadIdx.x + k * 256];
        atomicAdd(&h1[d.x >> 6], 1); atomicAdd(&h1[d.y >> 6], 1);
        atomicAdd(&h1[d.z >> 6], 1); atomicAdd(&h1[d.w >> 6], 1);
    }
    __syncthreads();
    // reserve per-bucket ranges: one global atomic per (block,bucket); counters 64B-padded
    for (int t = threadIdx.x; t < NB; t += 256) {
        int c = h1[t];
        base[t] = c ? atomicAdd(&gcount[t * 16], c) : 0;
    }
    __syncthreads();
    // pass 2: re-read (L2-hot) and place
#define PLACE(dv, sv, wv) { int b_ = (dv) >> 6; int off_ = atomicAdd(&h2[b_], 1); \
    sorted[(size_t)b_ * CAP + base[b_] + off_] = \
        make_uint2(((unsigned)(sv) << 6) | (unsigned)((dv) & 63), __float_as_uint(wv)); }
#pragma unroll
    for (int k = 0; k < 2; ++k) {
        int idx = threadIdx.x + k * 256;
        int4   s = sp[idx];
        int4   d = dp[idx];
        float4 wv = wp[idx];
        PLACE(d.x, s.x, wv.x) PLACE(d.y, s.y, wv.y)
        PLACE(d.z, s.z, wv.z) PLACE(d.w, s.w, wv.w)
    }
#undef PLACE
}

// ---------------- Fused: counting-sort + atomic-free aggregation + GRU + LSTM ----------------
// One block = one bucket of 64 nodes (~2048 edges).
__global__ __launch_bounds__(256) void aggnode_k(
    const uint2* __restrict__ sorted, const int* __restrict__ gcount,
    const float* __restrict__ m,
    const int* __restrict__ x, const float* __restrict__ emb,
    const float* __restrict__ h0g, const float* __restrict__ c0g,
    const float* __restrict__ gwi, const float* __restrict__ gwh,
    const float* __restrict__ gbi, const float* __restrict__ gbh,
    const float* __restrict__ lwi, const float* __restrict__ lwh,
    const float* __restrict__ lbi, const float* __restrict__ lbh,
    float* __restrict__ out_h, float* __restrict__ out_c, ushort* __restrict__ yb) {
    __shared__ uint2 sedge[CAP];                 // 20.5 KB: bucket edges sorted by dst-low
    __shared__ int   cnt[NPB], off[NPB], place[NPB];
    __shared__ float s_a[NPB * 17];
    __shared__ float s_ht[NPB * 17];
    __shared__ float s_gwi[768], s_gwh[768], s_gbi[48], s_gbh[48];
    __shared__ float s_lwi[2048], s_lwh[4096], s_lbi[128], s_lbh[128];

    int tid = threadIdx.x;
    if (tid < NPB) { cnt[tid] = 0; place[tid] = 0; }
    for (int t = tid; t < 768; t += 256) { s_gwi[t] = gwi[t]; s_gwh[t] = gwh[t]; }
    if (tid < 48) { s_gbi[tid] = gbi[tid]; s_gbh[tid] = gbh[tid]; }
    for (int t = tid; t < 2048; t += 256) s_lwi[t] = lwi[t];
    for (int t = tid; t < 4096; t += 256) s_lwh[t] = lwh[t];
    if (tid < 128) { s_lbi[tid] = lbi[tid]; s_lbh[tid] = lbh[tid]; }
    __syncthreads();

    int b = blockIdx.x;
    int nb = gcount[b * 16];
    const uint2* seg = sorted + (size_t)b * CAP;
    // ---- Phase A: count per dst-low ----
    for (int i = tid; i < nb; i += 256)
        atomicAdd(&cnt[seg[i].x & 63], 1);
    __syncthreads();
    // ---- Phase B: exclusive scan (wave 0; wave=64 lanes) ----
    if (tid < 64) {
        int c0 = cnt[tid];
        int c = c0;
#pragma unroll
        for (int o = 1; o < 64; o <<= 1) {
            int v = __shfl_up(c, o, 64);
            if (tid >= o) c += v;
        }
        off[tid] = c - c0;
    }
    __syncthreads();
    // ---- Phase C: place edges into LDS, grouped by dst-low (seg re-read is L2-hot) ----
    for (int i = tid; i < nb; i += 256) {
        uint2 ev = seg[i];
        int dl = ev.x & 63;
        int pos = off[dl] + atomicAdd(&place[dl], 1);
        sedge[pos] = ev;
    }
    __syncthreads();

    int n  = tid >> 2;        // node within bucket: 0..63
    int p  = tid & 3;         // part: 0..3
    int gn = b * NPB + n;     // global node
    // ---- Phase D: segmented reduction, 4 threads/node, no atomics ----
    {
        int s0 = off[n], deg = cnt[n];
        float a0 = 0.f, a1 = 0.f, a2 = 0.f, a3 = 0.f;
        const float4* m4 = (const float4*)m;
        for (int i = s0; i < s0 + deg; ++i) {
            uint2 ev = sedge[i];
            float w = __uint_as_float(ev.y);
            int src = ev.x >> 6;
            float4 v = m4[src * 4 + p];
            a0 += v.x * w; a1 += v.y * w; a2 += v.z * w; a3 += v.w * w;
        }
        float inv = 1.0f / fmaxf((float)deg, 1.0f);
        float* ap = &s_a[n * 17 + p * 4];
        ap[0] = a0 * inv; ap[1] = a1 * inv; ap[2] = a2 * inv; ap[3] = a3 * inv;
    }
    // xe = emb[x[gn]] (load while phase D settles)
    int xi = x[gn];
    float xe[16];
    {
        const float4* p2 = (const float4*)(emb + (size_t)xi * 16);
#pragma unroll
        for (int q = 0; q < 4; ++q) {
            float4 v = p2[q];
            xe[4*q] = v.x; xe[4*q+1] = v.y; xe[4*q+2] = v.z; xe[4*q+3] = v.w;
        }
    }
    __syncthreads();
    // ---- Phase E: GRU — 4 features per thread ----
    {
        const float* a = &s_a[n * 17];
#pragma unroll
        for (int ff = 0; ff < 4; ++ff) {
            int f = p * 4 + ff;
            float ir = s_gbi[f],    iz = s_gbi[16+f], in_ = s_gbi[32+f];
            float hr = s_gbh[f],    hz = s_gbh[16+f], hn  = s_gbh[32+f];
#pragma unroll
            for (int k = 0; k < 16; ++k) {
                float av = a[k], xv = xe[k];
                ir  += av * s_gwi[f*16 + k];
                iz  += av * s_gwi[(16+f)*16 + k];
                in_ += av * s_gwi[(32+f)*16 + k];
                hr  += xv * s_gwh[f*16 + k];
                hz  += xv * s_gwh[(16+f)*16 + k];
                hn  += xv * s_gwh[(32+f)*16 + k];
            }
            float r = sigf(ir + hr);
            float z = sigf(iz + hz);
            float nn2 = tanhf(in_ + r * hn);
            s_ht[n * 17 + f] = (1.0f - z) * nn2 + z * xe[f];
        }
    }
    __syncthreads();
    // ---- Phase F: LSTM — 8 outputs per thread ----
    {
        float h0v[32];
        const float4* ph = (const float4*)(h0g + (size_t)gn * 32);
#pragma unroll
        for (int q = 0; q < 8; ++q) {
            float4 v = ph[q];
            h0v[4*q] = v.x; h0v[4*q+1] = v.y; h0v[4*q+2] = v.z; h0v[4*q+3] = v.w;
        }
        float htv[16];
#pragma unroll
        for (int k = 0; k < 16; ++k) htv[k] = s_ht[n * 17 + k];
        float c0v[8];
        {
            float4 ca = *(const float4*)(c0g + (size_t)gn * 32 + p * 8);
            float4 cb = *(const float4*)(c0g + (size_t)gn * 32 + p * 8 + 4);
            c0v[0]=ca.x; c0v[1]=ca.y; c0v[2]=ca.z; c0v[3]=ca.w;
            c0v[4]=cb.x; c0v[5]=cb.y; c0v[6]=cb.z; c0v[7]=cb.w;
        }
        float cnv[8], hnv[8];
        ushort yv[8];
#pragma unroll
        for (int jj = 0; jj < 8; ++jj) {
            int j = p * 8 + jj;
            float ig = s_lbi[j]      + s_lbh[j];
            float fg = s_lbi[32+j]   + s_lbh[32+j];
            float gg = s_lbi[64+j]   + s_lbh[64+j];
            float og = s_lbi[96+j]   + s_lbh[96+j];
#pragma unroll
            for (int k = 0; k < 16; ++k) {
                float hv = htv[k];
                ig += hv * s_lwi[j*16 + k];
                fg += hv * s_lwi[(32+j)*16 + k];
                gg += hv * s_lwi[(64+j)*16 + k];
                og += hv * s_lwi[(96+j)*16 + k];
            }
#pragma unroll
            for (int k = 0; k < 32; ++k) {
                float hv = h0v[k];
                ig += hv * s_lwh[j*32 + k];
                fg += hv * s_lwh[(32+j)*32 + k];
                gg += hv * s_lwh[(64+j)*32 + k];
                og += hv * s_lwh[(96+j)*32 + k];
            }
            float cn  = sigf(fg) * c0v[jj] + sigf(ig) * tanhf(gg);
            float hn2 = sigf(og) * tanhf(cn);
            cnv[jj] = cn; hnv[jj] = hn2;
            __hip_bfloat16 t = __float2bfloat16(fmaxf(hn2, 0.0f));
            yv[jj] = *(ushort*)&t;
        }
        size_t ob = (size_t)gn * 32 + p * 8;
        *(float4*)(out_c + ob)     = make_float4(cnv[0],cnv[1],cnv[2],cnv[3]);
        *(float4*)(out_c + ob + 4) = make_float4(cnv[4],cnv[5],cnv[6],cnv[7]);
        *(float4*)(out_h + ob)     = make_float4(hnv[0],hnv[1],hnv[2],hnv[3]);
        *(float4*)(out_h + ob + 4) = make_float4(hnv[4],hnv[5],hnv[6],hnv[7]);
        uint4 yq;
        yq.x = (unsigned)yv[0] | ((unsigned)yv[1] << 16);
        yq.y = (unsigned)yv[2] | ((unsigned)yv[3] << 16);
        yq.z = (unsigned)yv[4] | ((unsigned)yv[5] << 16);
        yq.w = (unsigned)yv[6] | ((unsigned)yv[7] << 16);
        *(uint4*)(yb + ob) = yq;
    }
}

// ---------------- Kernel D: scores = y_u @ y_i^T via bf16 MFMA ----------------
// R6 version (measured equal-best): 64x256 block tile, LDS-transpose epilogue.
__global__ __launch_bounds__(256) void scores_mfma_k(const ushort* __restrict__ yb,
                                                     float* __restrict__ out) {
    __shared__ float tr[4][16][68];
    int tid = threadIdx.x;
    int w = tid >> 6, l = tid & 63;
    int bx = blockIdx.x & 63;     // 64 col-blocks of 256
    int by = blockIdx.x >> 6;     // 256 row-blocks of 64
    int row0 = by * 64 + w * 16;
    int col0 = bx * 256;
    int lr = l & 15;
    int lk = (l >> 4) << 3;       // 0,8,16,24
    bf16x8 a = *(const bf16x8*)(yb + (size_t)(row0 + lr) * 32 + lk);
    const ushort* yi = yb + (size_t)(UU + col0) * 32;
    f32x4 acc[16];
#pragma unroll
    for (int ct = 0; ct < 16; ++ct) {
        bf16x8 b = *(const bf16x8*)(yi + (size_t)(ct * 16 + lr) * 32 + lk);
        acc[ct] = __builtin_amdgcn_mfma_f32_16x16x32_bf16(a, b, (f32x4){0.0f,0.0f,0.0f,0.0f}, 0, 0, 0);
    }
    float* lw = &tr[w][0][0];
    int G = l >> 4;               // 0..3
#pragma unroll
    for (int g = 0; g < 4; ++g) {
#pragma unroll
        for (int ct2 = 0; ct2 < 4; ++ct2)
#pragma unroll
            for (int r = 0; r < 4; ++r)
                lw[(G * 4 + r) * 68 + ct2 * 16 + lr] = acc[g * 4 + ct2][r];
#pragma unroll
        for (int i = 0; i < 4; ++i) {
            int rl = 4 * i + G;
            float4 v = *(const float4*)&lw[rl * 68 + lr * 4];
            *(float4*)(out + (size_t)(row0 + rl) * UU + col0 + g * 64 + lr * 4) = v;
        }
    }
}

extern "C" void kernel_launch(void* const* d_in, const int* in_sizes, int n_in,
                              void* d_out, int out_size, void* d_ws, size_t ws_size,
                              hipStream_t stream) {
    const int*   x   = (const int*)d_in[0];
    const int*   e   = (const int*)d_in[1];
    const float* h   = (const float*)d_in[2];
    const float* h0  = (const float*)d_in[3];
    const float* c0  = (const float*)d_in[4];
    const float* emb = (const float*)d_in[5];
    const float* ggc = (const float*)d_in[6];
    const float* gwi = (const float*)d_in[7];
    const float* gwh = (const float*)d_in[8];
    const float* gbi = (const float*)d_in[9];
    const float* gbh = (const float*)d_in[10];
    const float* lwi = (const float*)d_in[11];
    const float* lwh = (const float*)d_in[12];
    const float* lbi = (const float*)d_in[13];
    const float* lbh = (const float*)d_in[14];

    float* out    = (float*)d_out;
    float* scores = out;
    float* out_h  = out + (size_t)UU * UU;
    float* out_c  = out_h + (size_t)NN * 32;

    char* ws = (char*)d_ws;
    float*  m       = (float*)(ws);                    // 2 MB
    ushort* yb      = (ushort*)(ws + (4u << 20));      // NN*32 bf16 = 2 MB
    int*    gcount  = (int*)  (ws + (8u << 20));       // 512 counters, 64B-padded = 32 KB

    // 512*2560*8B = 10.5 MB sorted-edge scratch inside the scores output
    // region (fully overwritten by scores_mfma_k afterwards).
    uint2* sorted  = (uint2*)((char*)d_out + (512u << 20));

    prep_m_k<<<NN / 256, 256, 0, stream>>>(x, emb, ggc, m, gcount);
    scatter_fused_k<<<SB2, 256, 0, stream>>>(e, h, gcount, sorted);
    aggnode_k<<<NB, 256, 0, stream>>>(sorted, gcount, m, x, emb, h0, c0,
                                      gwi, gwh, gbi, gbh,
                                      lwi, lwh, lbi, lbh,
                                      out_h, out_c, yb);
    scores_mfma_k<<<256 * 64, 256, 0, stream>>>(yb, scores);
}